// Round 1
// baseline (33654.922 us; speedup 1.0000x reference)
//
#include <hip/hip_runtime.h>
#include <stdint.h>

// SpatialGRU on MI355X. Wavefront over anti-diagonals: 159 launches, grid=80
// (block r == cell column; stable blockIdx -> stable XCD -> L2 reuse of the
// strided inputs gather across consecutive diagonals). One workgroup (256 thr,
// 4 waves) per cell. GEMMs via mfma_f32_16x16x32_bf16 computing C^T
// (A = packed weights, B = q^T from LDS). fp32 h carry in ring buffers.

typedef __bf16 bf16x8 __attribute__((ext_vector_type(8)));
typedef float  f32x4  __attribute__((ext_vector_type(4)));
typedef unsigned short ushort4v __attribute__((ext_vector_type(4)));

#define QPITCH 424   // 416 q cols + 8 pad (bf16 elems); row stride 848 B

__device__ __forceinline__ unsigned short f2bf(float x) {
  unsigned int u = __builtin_bit_cast(unsigned int, x);
  u = u + 0x7FFFu + ((u >> 16) & 1u);          // round-to-nearest-even
  return (unsigned short)(u >> 16);
}
__device__ __forceinline__ float bf2f(unsigned short h) {
  unsigned int u = ((unsigned int)h) << 16;
  return __builtin_bit_cast(float, u);
}
__device__ __forceinline__ float sigm(float x) {
  x = fminf(fmaxf(x, -30.f), 30.f);
  return 1.f / (1.f + __expf(-x));
}
__device__ __forceinline__ float tanh_fast(float x) {
  x = fminf(fmaxf(x, -15.f), 15.f);
  float e = __expf(2.f * x);
  return (e - 1.f) / (e + 1.f);
}

// ---------------------------------------------------------------------------
// prep: pack fused weight matrix W' (1024 x 416) and WU' (128 x 384) into
// MFMA A-fragment order: chunk(kb, nt)[lane][8] = W[nt*16 + (lane&15)]
//                                                 [kb*32 + (lane>>4)*8 + j].
// Fused n-layout: 0..383 = Wr rows; 384..895 = Wz rows interleaved as
// n = 384 + 4*u + gate (softmax groups land in one lane's 4 acc regs);
// 896..1023 = Wij rows (nonzero only for k in 384..415 = s_ij columns).
// WU' has its k blocks 0<->1 swapped (hl,ht,hd -> q order ht,hl,hd) so the
// r*h A2 build is a pure in-place column RMW in LDS.
// ---------------------------------------------------------------------------
__global__ void prep_kernel(const float* __restrict__ Wr, const float* __restrict__ Wz,
                            const float* __restrict__ Wij, const float* __restrict__ WU,
                            const float* __restrict__ br, const float* __restrict__ bz,
                            const float* __restrict__ bij,
                            unsigned short* __restrict__ wp1, unsigned short* __restrict__ wp2,
                            float* __restrict__ bfused) {
  int blk = blockIdx.x, lane = threadIdx.x;
  if (blk < 832) {                       // 13 kb * 64 ntiles for W'
    int kb = blk >> 6, nt = blk & 63;
    int n = nt * 16 + (lane & 15);
    int kb8 = kb * 32 + (lane >> 4) * 8;
    unsigned short v[8];
#pragma unroll
    for (int j = 0; j < 8; ++j) {
      int k = kb8 + j; float w;
      if (n < 384) w = Wr[n * 416 + k];
      else if (n < 896) { int u = (n - 384) >> 2, g = (n - 384) & 3; w = Wz[(g * 128 + u) * 416 + k]; }
      else { int u = n - 896; w = (k >= 384) ? Wij[u * 32 + (k - 384)] : 0.f; }
      v[j] = f2bf(w);
    }
    ushort4v* dst = (ushort4v*)(wp1 + ((size_t)(kb * 64 + nt) * 64 + lane) * 8);
    dst[0] = (ushort4v){v[0], v[1], v[2], v[3]};
    dst[1] = (ushort4v){v[4], v[5], v[6], v[7]};
  } else if (blk < 832 + 96) {           // 12 kb * 8 ntiles for WU'
    int b2 = blk - 832;
    int kb = b2 >> 3, nt = b2 & 7;
    int n = nt * 16 + (lane & 15);
    int kb8 = kb * 32 + (lane >> 4) * 8;
    unsigned short v[8];
#pragma unroll
    for (int j = 0; j < 8; ++j) {
      int c = kb8 + j;
      int s = (c < 128) ? c + 128 : (c < 256 ? c - 128 : c);  // block swap
      v[j] = f2bf(WU[n * 384 + s]);
    }
    ushort4v* dst = (ushort4v*)(wp2 + ((size_t)(kb * 8 + nt) * 64 + lane) * 8);
    dst[0] = (ushort4v){v[0], v[1], v[2], v[3]};
    dst[1] = (ushort4v){v[4], v[5], v[6], v[7]};
  } else {                               // fused bias (1024 fp32)
#pragma unroll
    for (int i = 0; i < 16; ++i) {
      int n = lane * 16 + i; float v;
      if (n < 384) v = br[n];
      else if (n < 896) { int u = (n - 384) >> 2, g = (n - 384) & 3; v = bz[g * 128 + u]; }
      else v = bij[n - 896];
      bfused[n] = v;
    }
  }
}

// ---------------------------------------------------------------------------
// One cell per workgroup. d = diagonal index (l + r). Ring: 3 slots of
// [80 cells][128 b][128 u] fp32. Scratch per cell: hz, zi, cwij (each 64 KB).
// ---------------------------------------------------------------------------
__global__ __launch_bounds__(256, 1)
void diag_kernel(int d, const float* __restrict__ x, const float* __restrict__ bfused,
                 const unsigned short* __restrict__ wp1, const unsigned short* __restrict__ wp2,
                 float* __restrict__ ring, float* __restrict__ scratch,
                 float* __restrict__ out) {
  const int rc = blockIdx.x;
  const int l = d - rc;
  if (l < 0 || l >= 80) return;
  extern __shared__ unsigned short lds[];          // qA[128][QPITCH] bf16
  const int tid = threadIdx.x;
  const int wave = tid >> 6, lane = tid & 63;
  const int quad = lane >> 4, l15 = lane & 15;

  const bool vt = (l >= 1), vlft = (rc >= 1), vdg = vt && vlft;
  const float* slot1 = ring + (size_t)(((d + 2) % 3) * 80) * 16384;  // diag d-1
  const float* slot2 = ring + (size_t)(((d + 1) % 3) * 80) * 16384;  // diag d-2
  float* slotw = ring + ((size_t)((d % 3) * 80 + rc)) * 16384;
  const float* htopP  = slot1 + (size_t)rc * 16384;
  const float* hleftP = slot1 + (size_t)(rc - 1) * 16384;
  const float* hdiagP = slot2 + (size_t)(rc - 1) * 16384;

  // ---- stage q = [h_top | h_left | h_diag | s_ij] into LDS as bf16 ----
#pragma unroll
  for (int blkI = 0; blkI < 3; ++blkI) {
    const float* src = (blkI == 0) ? htopP : (blkI == 1 ? hleftP : hdiagP);
    const bool valid = (blkI == 0) ? vt : (blkI == 1 ? vlft : vdg);
#pragma unroll
    for (int i = 0; i < 16; ++i) {
      int idx = i * 256 + tid;                 // 4096 float4 groups
      int b = idx >> 5, c4 = (idx & 31) << 2;
      unsigned short* dst = lds + (size_t)b * QPITCH + blkI * 128 + c4;
      ushort4v o;
      if (valid) {
        float4 v = *(const float4*)(src + b * 128 + c4);
        o = (ushort4v){f2bf(v.x), f2bf(v.y), f2bf(v.z), f2bf(v.w)};
      } else {
        o = (ushort4v){0, 0, 0, 0};
      }
      *(ushort4v*)dst = o;
    }
  }
  {
    const float* xb = x + (size_t)l * 80 + rc;   // inputs[b][c][l][rc]
#pragma unroll
    for (int i = 0; i < 16; ++i) {
      int idx = i * 256 + tid;                   // idx = b*32 + c
      int b = idx >> 5, c = idx & 31;
      lds[(size_t)b * QPITCH + 384 + c] = f2bf(xb[(size_t)idx * 6400]);
    }
  }
  __syncthreads();

  float* scr  = scratch + (size_t)rc * 49152;
  float* hz_s = scr;                 // [u][b] fp32
  float* zi_s = scr + 16384;
  float* cw_s = scr + 32768;

  f32x4 acc[8][8];                   // wave tile: 128 n-rows x 128 b-cols

  // pass 0: n in [512,1024) = z(u>=32) + wij ; pass 1: n in [0,512) = r + z(u<32)
#pragma unroll 1
  for (int pass = 0; pass < 2; ++pass) {
    const int nsl = (pass == 0 ? 512 : 0) + wave * 128;
#pragma unroll
    for (int mt = 0; mt < 8; ++mt)
#pragma unroll
      for (int bt = 0; bt < 8; ++bt) acc[mt][bt] = (f32x4){0.f, 0.f, 0.f, 0.f};

    const int ntb = nsl >> 4;
    for (int kb = 0; kb < 13; ++kb) {
      bf16x8 wf[8], qf[8];
#pragma unroll
      for (int mt = 0; mt < 8; ++mt)
        wf[mt] = *(const bf16x8*)(wp1 + ((size_t)(kb * 64 + ntb + mt) * 64 + lane) * 8);
#pragma unroll
      for (int bt = 0; bt < 8; ++bt)
        qf[bt] = *(const bf16x8*)(lds + (size_t)(bt * 16 + l15) * QPITCH + kb * 32 + quad * 8);
#pragma unroll
      for (int mt = 0; mt < 8; ++mt)
#pragma unroll
        for (int bt = 0; bt < 8; ++bt)
          acc[mt][bt] = __builtin_amdgcn_mfma_f32_16x16x32_bf16(wf[mt], qf[bt], acc[mt][bt], 0, 0, 0);
    }
    __syncthreads();   // pass1: separates all waves' q reads from A2 in-place writes

    if (nsl >= 896) {
      // ---- wij class: cwij = acc + bij ----
#pragma unroll
      for (int mt = 0; mt < 8; ++mt)
#pragma unroll
        for (int bt = 0; bt < 8; ++bt) {
          int b = bt * 16 + l15;
#pragma unroll
          for (int g = 0; g < 4; ++g) {
            int n = nsl + mt * 16 + quad * 4 + g;
            cw_s[(n - 896) * 128 + b] = acc[mt][bt][g] + bfused[n];
          }
        }
    } else if (nsl >= 384) {
      // ---- z class: lane-local softmax over 4 gates; fold fp32 h's ----
#pragma unroll
      for (int mt = 0; mt < 8; ++mt)
#pragma unroll
        for (int bt = 0; bt < 8; ++bt) {
          int nb = nsl + mt * 16 + quad * 4;
          int u = (nb - 384) >> 2;
          int b = bt * 16 + l15;
          float v0 = acc[mt][bt][0] + bfused[nb];
          float v1 = acc[mt][bt][1] + bfused[nb + 1];
          float v2 = acc[mt][bt][2] + bfused[nb + 2];
          float v3 = acc[mt][bt][3] + bfused[nb + 3];
          float m = fmaxf(fmaxf(v0, v1), fmaxf(v2, v3));
          float e0 = __expf(v0 - m), e1 = __expf(v1 - m);
          float e2 = __expf(v2 - m), e3 = __expf(v3 - m);
          float inv = 1.f / (e0 + e1 + e2 + e3);
          float hl = vlft ? hleftP[b * 128 + u] : 0.f;
          float ht = vt   ? htopP [b * 128 + u] : 0.f;
          float hd = vdg  ? hdiagP[b * 128 + u] : 0.f;
          hz_s[u * 128 + b] = (e1 * hl + e2 * ht + e3 * hd) * inv;  // zl,zt,zd
          zi_s[u * 128 + b] = e0 * inv;
        }
    } else {
      // ---- r class: sigmoid in place; r stays in acc regs for A2 ----
#pragma unroll
      for (int mt = 0; mt < 8; ++mt)
#pragma unroll
        for (int bt = 0; bt < 8; ++bt) {
#pragma unroll
          for (int g = 0; g < 4; ++g) {
            int n = nsl + mt * 16 + quad * 4 + g;
            acc[mt][bt][g] = sigm(acc[mt][bt][g] + bfused[n]);
          }
        }
    }
  }

  // ---- A2' = r' * q, built in place in LDS (q-order; perm folded into WU')
  // wave0 holds r[0..127] (pairs h_left = q cols 128..255) -> writes cols+128
  // wave1 holds r[128..255] (pairs h_top = q cols 0..127) -> writes cols-128
  // wave2 holds r[256..383] (pairs h_diag) -> same cols. Pure per-lane RMW.
  if (wave < 3) {
    const int base = (wave == 0) ? 128 : (wave == 1 ? 0 : 256);
#pragma unroll
    for (int mt = 0; mt < 8; ++mt)
#pragma unroll
      for (int bt = 0; bt < 8; ++bt) {
        int col = base + mt * 16 + quad * 4;
        int row = bt * 16 + l15;
        unsigned short* p = lds + (size_t)row * QPITCH + col;
        ushort4v qv = *(ushort4v*)p;
        ushort4v o;
#pragma unroll
        for (int g = 0; g < 4; ++g)
          o[g] = f2bf(bf2f(qv[g]) * acc[mt][bt][g]);
        *(ushort4v*)p = o;
      }
  }
  __syncthreads();

  // ---- GEMM2: hU^T = WU' @ A2'^T (M=128 u, K=384, N=128 b) ----
  f32x4 acc2[2][8];
#pragma unroll
  for (int mt = 0; mt < 2; ++mt)
#pragma unroll
    for (int bt = 0; bt < 8; ++bt) acc2[mt][bt] = (f32x4){0.f, 0.f, 0.f, 0.f};
  for (int kb = 0; kb < 12; ++kb) {
    bf16x8 wf[2], qf[8];
#pragma unroll
    for (int mt = 0; mt < 2; ++mt)
      wf[mt] = *(const bf16x8*)(wp2 + ((size_t)(kb * 8 + wave * 2 + mt) * 64 + lane) * 8);
#pragma unroll
    for (int bt = 0; bt < 8; ++bt)
      qf[bt] = *(const bf16x8*)(lds + (size_t)(bt * 16 + l15) * QPITCH + kb * 32 + quad * 8);
#pragma unroll
    for (int mt = 0; mt < 2; ++mt)
#pragma unroll
      for (int bt = 0; bt < 8; ++bt)
        acc2[mt][bt] = __builtin_amdgcn_mfma_f32_16x16x32_bf16(wf[mt], qf[bt], acc2[mt][bt], 0, 0, 0);
  }

  // ---- combine: h = hz + zi * tanh(cwij + hU); write fp32 ring (+out) ----
#pragma unroll
  for (int mt = 0; mt < 2; ++mt)
#pragma unroll
    for (int bt = 0; bt < 8; ++bt) {
      int b = bt * 16 + l15;
#pragma unroll
      for (int g = 0; g < 4; ++g) {
        int u = wave * 32 + mt * 16 + quad * 4 + g;
        float hhat = tanh_fast(cw_s[u * 128 + b] + acc2[mt][bt][g]);
        float h = hz_s[u * 128 + b] + zi_s[u * 128 + b] * hhat;
        slotw[b * 128 + u] = h;
        if (d == 158) out[b * 128 + u] = h;
      }
    }
}

// ---------------------------------------------------------------------------
extern "C" void kernel_launch(void* const* d_in, const int* in_sizes, int n_in,
                              void* d_out, int out_size, void* d_ws, size_t ws_size,
                              hipStream_t stream) {
  const float* x   = (const float*)d_in[0];
  const float* Wr  = (const float*)d_in[1];
  const float* br  = (const float*)d_in[2];
  const float* Wz  = (const float*)d_in[3];
  const float* bz  = (const float*)d_in[4];
  const float* Wij = (const float*)d_in[5];
  const float* bij = (const float*)d_in[6];
  const float* WU  = (const float*)d_in[7];
  float* out = (float*)d_out;

  // ws layout (total ~32.4 MB)
  char* ws = (char*)d_ws;
  unsigned short* wp1 = (unsigned short*)(ws);                 // 851,968 B
  unsigned short* wp2 = (unsigned short*)(ws + 851968);        //  98,304 B
  float* bfused       = (float*)(ws + 950272);                 //   4,096 B
  float* ring         = (float*)(ws + 954368);                 // 15,728,640 B
  float* scratch      = (float*)(ws + 954368 + 15728640);      // 15,728,640 B

  (void)hipFuncSetAttribute((const void*)diag_kernel,
                            hipFuncAttributeMaxDynamicSharedMemorySize, 128 * QPITCH * 2);

  prep_kernel<<<929, 64, 0, stream>>>(Wr, Wz, Wij, WU, br, bz, bij, wp1, wp2, bfused);
  for (int d = 0; d < 159; ++d)
    diag_kernel<<<80, 256, 128 * QPITCH * 2, stream>>>(d, x, bfused, wp1, wp2, ring, scratch, out);
}

// Round 2
// 5897.379 us; speedup vs baseline: 5.7068x; 5.7068x over previous
//
#include <hip/hip_runtime.h>
#include <stdint.h>

// SpatialGRU on MI355X, round 2. Wavefront over anti-diagonals: 159 launches.
// Batch split in two: grid=160, cell rc = blk%80, half bh = blk/80 (80%8==0
// keeps both halves of a cell on the same XCD -> shared L2 weight lines).
// 1024 threads (16 waves) per block; wave tile 64n x 64b -> acc[4][4] = 64
// VGPRs (round 1's acc[8][8]=256 maxed arch VGPRs and spilled; 1-wave/SIMD
// occupancy exposed every latency -> 212us/dispatch). A 1024-thread block
// forces <=128 regs/wave (4 waves/SIMD resident) and gives latency hiding.

typedef __bf16 bf16x8 __attribute__((ext_vector_type(8)));
typedef float  f32x4  __attribute__((ext_vector_type(4)));
typedef unsigned short ushort4v __attribute__((ext_vector_type(4)));
typedef unsigned short ushort2v __attribute__((ext_vector_type(2)));

#define QPITCH 424   // 416 q cols + 8 pad (bf16 elems)

__device__ __forceinline__ unsigned short f2bf(float x) {
  unsigned int u = __builtin_bit_cast(unsigned int, x);
  u = u + 0x7FFFu + ((u >> 16) & 1u);          // round-to-nearest-even
  return (unsigned short)(u >> 16);
}
__device__ __forceinline__ float bf2f(unsigned short h) {
  unsigned int u = ((unsigned int)h) << 16;
  return __builtin_bit_cast(float, u);
}
__device__ __forceinline__ float sigm(float x) {
  x = fminf(fmaxf(x, -30.f), 30.f);
  return 1.f / (1.f + __expf(-x));
}
__device__ __forceinline__ float tanh_fast(float x) {
  x = fminf(fmaxf(x, -15.f), 15.f);
  float e = __expf(2.f * x);
  return (e - 1.f) / (e + 1.f);
}

// ---------------------------------------------------------------------------
// prep: pack fused W' (1024 x 416) and WU' (128 x 384) into MFMA A-fragment
// order: chunk(kb, nt)[lane][8] = W[nt*16 + (lane&15)][kb*32 + (lane>>4)*8 + j].
// Fused n-layout: 0..383 Wr; 384..895 Wz interleaved n=384+4u+gate (softmax
// group lands in one lane's 4 acc regs); 896..1023 Wij (nonzero only k>=384).
// WU' k-blocks 0<->1 swapped (hl,ht,hd -> q order ht,hl,hd) so the r*h A2
// build is a pure in-place column RMW in LDS.
// ---------------------------------------------------------------------------
__global__ void prep_kernel(const float* __restrict__ Wr, const float* __restrict__ Wz,
                            const float* __restrict__ Wij, const float* __restrict__ WU,
                            const float* __restrict__ br, const float* __restrict__ bz,
                            const float* __restrict__ bij,
                            unsigned short* __restrict__ wp1, unsigned short* __restrict__ wp2,
                            float* __restrict__ bfused) {
  int blk = blockIdx.x, lane = threadIdx.x;
  if (blk < 832) {                       // 13 kb * 64 ntiles for W'
    int kb = blk >> 6, nt = blk & 63;
    int n = nt * 16 + (lane & 15);
    int kb8 = kb * 32 + (lane >> 4) * 8;
    unsigned short v[8];
#pragma unroll
    for (int j = 0; j < 8; ++j) {
      int k = kb8 + j; float w;
      if (n < 384) w = Wr[n * 416 + k];
      else if (n < 896) { int u = (n - 384) >> 2, g = (n - 384) & 3; w = Wz[(g * 128 + u) * 416 + k]; }
      else { int u = n - 896; w = (k >= 384) ? Wij[u * 32 + (k - 384)] : 0.f; }
      v[j] = f2bf(w);
    }
    ushort4v* dst = (ushort4v*)(wp1 + ((size_t)(kb * 64 + nt) * 64 + lane) * 8);
    dst[0] = (ushort4v){v[0], v[1], v[2], v[3]};
    dst[1] = (ushort4v){v[4], v[5], v[6], v[7]};
  } else if (blk < 832 + 96) {           // 12 kb * 8 ntiles for WU'
    int b2 = blk - 832;
    int kb = b2 >> 3, nt = b2 & 7;
    int n = nt * 16 + (lane & 15);
    int kb8 = kb * 32 + (lane >> 4) * 8;
    unsigned short v[8];
#pragma unroll
    for (int j = 0; j < 8; ++j) {
      int c = kb8 + j;
      int s = (c < 128) ? c + 128 : (c < 256 ? c - 128 : c);  // block swap
      v[j] = f2bf(WU[n * 384 + s]);
    }
    ushort4v* dst = (ushort4v*)(wp2 + ((size_t)(kb * 8 + nt) * 64 + lane) * 8);
    dst[0] = (ushort4v){v[0], v[1], v[2], v[3]};
    dst[1] = (ushort4v){v[4], v[5], v[6], v[7]};
  } else {                               // fused bias (1024 fp32)
#pragma unroll
    for (int i = 0; i < 16; ++i) {
      int n = lane * 16 + i; float v;
      if (n < 384) v = br[n];
      else if (n < 896) { int u = (n - 384) >> 2, g = (n - 384) & 3; v = bz[g * 128 + u]; }
      else v = bij[n - 896];
      bfused[n] = v;
    }
  }
}

// ---------------------------------------------------------------------------
// One (cell, batch-half) per workgroup; 16 waves.
// GEMM1: wave w covers n in [64w, 64w+64): w 0..5 = r, 6..13 = z, 14..15 = wij.
// Ring: 3 slots of [80 cells][128 b][128 u] fp32.
// Scratch per (cell,half): hz, zi, cw fp32 [64 bl][128 u] (32 KB each).
// ---------------------------------------------------------------------------
__global__ __launch_bounds__(1024)
void diag_kernel(int d, const float* __restrict__ x, const float* __restrict__ bfused,
                 const unsigned short* __restrict__ wp1, const unsigned short* __restrict__ wp2,
                 float* __restrict__ ring, float* __restrict__ scratch,
                 float* __restrict__ out) {
  const int blk = blockIdx.x;
  const int rc = (blk < 80) ? blk : blk - 80;
  const int bh = (blk < 80) ? 0 : 1;
  const int l = d - rc;
  if (l < 0 || l >= 80) return;
  extern __shared__ unsigned short lds[];          // q[64][QPITCH] bf16
  const int tid = threadIdx.x;
  const int wave = tid >> 6, lane = tid & 63;
  const int quad = lane >> 4, l15 = lane & 15;

  const bool vt = (l >= 1), vlft = (rc >= 1), vdg = vt && vlft;
  const float* slot1 = ring + (size_t)(((d + 2) % 3) * 80) * 16384;  // diag d-1
  const float* slot2 = ring + (size_t)(((d + 1) % 3) * 80) * 16384;  // diag d-2
  float* slotw = ring + ((size_t)((d % 3) * 80 + rc)) * 16384;
  const float* htopP  = slot1 + (size_t)rc * 16384;
  const float* hleftP = slot1 + (size_t)(rc - 1) * 16384;
  const float* hdiagP = slot2 + (size_t)(rc - 1) * 16384;

  // ---- stage q = [h_top | h_left | h_diag | s_ij] into LDS as bf16 ----
#pragma unroll
  for (int blkI = 0; blkI < 3; ++blkI) {
    const float* src = ((blkI == 0) ? htopP : (blkI == 1 ? hleftP : hdiagP)) + (size_t)bh * 64 * 128;
    const bool valid = (blkI == 0) ? vt : (blkI == 1 ? vlft : vdg);
#pragma unroll
    for (int it = 0; it < 2; ++it) {
      int idx = it * 1024 + tid;                 // 2048 float4 groups
      int b = idx >> 5, c4 = (idx & 31) << 2;
      ushort4v o = (ushort4v){0, 0, 0, 0};
      if (valid) {
        float4 v = *(const float4*)(src + b * 128 + c4);
        o = (ushort4v){f2bf(v.x), f2bf(v.y), f2bf(v.z), f2bf(v.w)};
      }
      *(ushort4v*)(lds + (size_t)b * QPITCH + blkI * 128 + c4) = o;
    }
  }
  {
    const float* xb = x + (size_t)l * 80 + rc;   // inputs[b][c][l][rc]
    int idx = tid * 2;                           // idx = b_local*32 + c
    int b = idx >> 5, c = idx & 31;
    float v0 = xb[(size_t)(bh * 2048 + idx) * 6400];
    float v1 = xb[(size_t)(bh * 2048 + idx + 1) * 6400];
    *(ushort2v*)(lds + (size_t)b * QPITCH + 384 + c) = (ushort2v){f2bf(v0), f2bf(v1)};
  }
  __syncthreads();

  // ---- GEMM1: fused [r|z|wij]^T = W' @ q^T, wave tile 64n x 64b ----
  f32x4 acc[4][4];
#pragma unroll
  for (int mt = 0; mt < 4; ++mt)
#pragma unroll
    for (int bt = 0; bt < 4; ++bt) acc[mt][bt] = (f32x4){0.f, 0.f, 0.f, 0.f};

  const int ntb = wave * 4;
  for (int kb = 0; kb < 13; ++kb) {
    bf16x8 wf[4], qf[4];
#pragma unroll
    for (int mt = 0; mt < 4; ++mt)
      wf[mt] = *(const bf16x8*)(wp1 + ((size_t)(kb * 64 + ntb + mt) * 64 + lane) * 8);
#pragma unroll
    for (int bt = 0; bt < 4; ++bt)
      qf[bt] = *(const bf16x8*)(lds + (size_t)(bt * 16 + l15) * QPITCH + kb * 32 + quad * 8);
#pragma unroll
    for (int mt = 0; mt < 4; ++mt)
#pragma unroll
      for (int bt = 0; bt < 4; ++bt)
        acc[mt][bt] = __builtin_amdgcn_mfma_f32_16x16x32_bf16(wf[mt], qf[bt], acc[mt][bt], 0, 0, 0);
  }
  __syncthreads();   // all q reads done before the in-place A2 RMW

  float* scr  = scratch + (size_t)(rc * 2 + bh) * 24576;
  float* hz_s = scr;                 // [bl][u] fp32
  float* zi_s = scr + 8192;
  float* cw_s = scr + 16384;

  if (wave < 6) {
    // ---- r class: sigmoid, then A2' = r*q in place in LDS.
    // r-col c of hcat=[hl|ht|hd] maps to q col: c<128 -> c+128; <256 -> c-128;
    // else c. Wave-uniform shift (wave spans 64 n within one 128-block).
    const int rn0 = wave * 64;
    const int shift = (rn0 < 128) ? 128 : (rn0 < 256 ? -128 : 0);
#pragma unroll
    for (int mt = 0; mt < 4; ++mt)
#pragma unroll
      for (int bt = 0; bt < 4; ++bt) {
        int n0 = rn0 + mt * 16 + quad * 4;
        int row = bt * 16 + l15;
        unsigned short* p = lds + (size_t)row * QPITCH + n0 + shift;
        ushort4v qv = *(ushort4v*)p;
        ushort4v o;
#pragma unroll
        for (int g = 0; g < 4; ++g) {
          float r = sigm(acc[mt][bt][g] + bfused[n0 + g]);
          o[g] = f2bf(bf2f(qv[g]) * r);
        }
        *(ushort4v*)p = o;
      }
  } else if (wave < 14) {
    // ---- z class: lane-local softmax over 4 gates; fold fp32 h's ----
#pragma unroll
    for (int mt = 0; mt < 4; ++mt)
#pragma unroll
      for (int bt = 0; bt < 4; ++bt) {
        int nb = wave * 64 + mt * 16 + quad * 4;
        int u = (nb - 384) >> 2;
        int bl = bt * 16 + l15;
        int bg = bh * 64 + bl;
        float v0 = acc[mt][bt][0] + bfused[nb];
        float v1 = acc[mt][bt][1] + bfused[nb + 1];
        float v2 = acc[mt][bt][2] + bfused[nb + 2];
        float v3 = acc[mt][bt][3] + bfused[nb + 3];
        float m = fmaxf(fmaxf(v0, v1), fmaxf(v2, v3));
        float e0 = __expf(v0 - m), e1 = __expf(v1 - m);
        float e2 = __expf(v2 - m), e3 = __expf(v3 - m);
        float inv = 1.f / (e0 + e1 + e2 + e3);
        float hl = vlft ? hleftP[bg * 128 + u] : 0.f;
        float ht = vt   ? htopP [bg * 128 + u] : 0.f;
        float hd = vdg  ? hdiagP[bg * 128 + u] : 0.f;
        hz_s[bl * 128 + u] = (e1 * hl + e2 * ht + e3 * hd) * inv;  // zl,zt,zd
        zi_s[bl * 128 + u] = e0 * inv;
      }
  } else {
    // ---- wij class: cw = acc + bij ----
#pragma unroll
    for (int mt = 0; mt < 4; ++mt)
#pragma unroll
      for (int bt = 0; bt < 4; ++bt) {
        int n0 = wave * 64 + mt * 16 + quad * 4;
        int uw = n0 - 896;
        int bl = bt * 16 + l15;
        f32x4 o;
#pragma unroll
        for (int g = 0; g < 4; ++g) o[g] = acc[mt][bt][g] + bfused[n0 + g];
        *(f32x4*)(cw_s + bl * 128 + uw) = o;
      }
  }
  __syncthreads();

  // ---- GEMM2: hU^T = WU' @ A2'^T (M=128 u, K=384, N=64 bl) ----
  const int m2 = wave >> 1, bsel = wave & 1;
  f32x4 acc2[2];
  acc2[0] = (f32x4){0.f, 0.f, 0.f, 0.f};
  acc2[1] = (f32x4){0.f, 0.f, 0.f, 0.f};
  for (int kb = 0; kb < 12; ++kb) {
    bf16x8 wf = *(const bf16x8*)(wp2 + ((size_t)(kb * 8 + m2) * 64 + lane) * 8);
    bf16x8 q0 = *(const bf16x8*)(lds + (size_t)((bsel * 2 + 0) * 16 + l15) * QPITCH + kb * 32 + quad * 8);
    bf16x8 q1 = *(const bf16x8*)(lds + (size_t)((bsel * 2 + 1) * 16 + l15) * QPITCH + kb * 32 + quad * 8);
    acc2[0] = __builtin_amdgcn_mfma_f32_16x16x32_bf16(wf, q0, acc2[0], 0, 0, 0);
    acc2[1] = __builtin_amdgcn_mfma_f32_16x16x32_bf16(wf, q1, acc2[1], 0, 0, 0);
  }

  // ---- combine: h = hz + zi * tanh(cw + hU); write fp32 ring (+out) ----
#pragma unroll
  for (int bt = 0; bt < 2; ++bt) {
    int bl = (bsel * 2 + bt) * 16 + l15;
    int u0 = m2 * 16 + quad * 4;
    f32x4 cw = *(f32x4*)(cw_s + bl * 128 + u0);
    f32x4 hz = *(f32x4*)(hz_s + bl * 128 + u0);
    f32x4 zi = *(f32x4*)(zi_s + bl * 128 + u0);
    f32x4 h;
#pragma unroll
    for (int g = 0; g < 4; ++g)
      h[g] = hz[g] + zi[g] * tanh_fast(cw[g] + acc2[bt][g]);
    *(f32x4*)(slotw + (size_t)(bh * 64 + bl) * 128 + u0) = h;
    if (d == 158) *(f32x4*)(out + (size_t)(bh * 64 + bl) * 128 + u0) = h;
  }
}

// ---------------------------------------------------------------------------
extern "C" void kernel_launch(void* const* d_in, const int* in_sizes, int n_in,
                              void* d_out, int out_size, void* d_ws, size_t ws_size,
                              hipStream_t stream) {
  const float* x   = (const float*)d_in[0];
  const float* Wr  = (const float*)d_in[1];
  const float* br  = (const float*)d_in[2];
  const float* Wz  = (const float*)d_in[3];
  const float* bz  = (const float*)d_in[4];
  const float* Wij = (const float*)d_in[5];
  const float* bij = (const float*)d_in[6];
  const float* WU  = (const float*)d_in[7];
  float* out = (float*)d_out;

  // ws layout (total ~32.4 MB)
  char* ws = (char*)d_ws;
  unsigned short* wp1 = (unsigned short*)(ws);                 // 851,968 B
  unsigned short* wp2 = (unsigned short*)(ws + 851968);        //  98,304 B
  float* bfused       = (float*)(ws + 950272);                 //   4,096 B
  float* ring         = (float*)(ws + 954368);                 // 15,728,640 B
  float* scratch      = (float*)(ws + 954368 + 15728640);      // 15,728,640 B

  (void)hipFuncSetAttribute((const void*)diag_kernel,
                            hipFuncAttributeMaxDynamicSharedMemorySize, 64 * QPITCH * 2);

  prep_kernel<<<929, 64, 0, stream>>>(Wr, Wz, Wij, WU, br, bz, bij, wp1, wp2, bfused);
  for (int d = 0; d < 159; ++d)
    diag_kernel<<<160, 1024, 64 * QPITCH * 2, stream>>>(d, x, bfused, wp1, wp2, ring, scratch, out);
}